// Round 5
// baseline (218.550 us; speedup 1.0000x reference)
//
#include <hip/hip_runtime.h>

typedef __bf16 bf16;
typedef __attribute__((ext_vector_type(4))) __bf16 bf16x4;
typedef __attribute__((ext_vector_type(8))) __bf16 bf16x8;
typedef __attribute__((ext_vector_type(4))) float f32x4;

#define MFMA(A,B,C) __builtin_amdgcn_mfma_f32_16x16x32_bf16(A,B,C,0,0,0)

#define SEQ 2048
#define EMB 512
#define HD  64
#define SCALE 22.627416997969522f  // sqrt(512): scores are divided by E^-0.5
// Online-softmax seed: not -inf (fast-math folds inf constants to poison).
#define NEG_SEED -3.0e4f

// ---------------------------------------------------------------------------
// One-shot fp32 -> bf16 hi/lo conversion (x, W_qkv) and bf16 (W_out).
// ---------------------------------------------------------------------------
__global__ __launch_bounds__(256)
void convert_kernel(const float* __restrict__ x, const float* __restrict__ Wqkv,
                    const float* __restrict__ Wout,
                    bf16* __restrict__ Xh, bf16* __restrict__ Xl,
                    bf16* __restrict__ Wqh, bf16* __restrict__ Wql,
                    bf16* __restrict__ Wo) {
  const int NX = 8192 * 512 / 4;   // f32x4 chunks
  const int NW = 1536 * 512 / 4;
  const int NO = 512 * 512 / 4;
  const int stride = gridDim.x * 256;
  for (int i = blockIdx.x * 256 + threadIdx.x; i < NX + NW + NO; i += stride) {
    const float* src; bf16 *dh, *dl; int j; bool haslo;
    if (i < NX)           { src = x;    dh = Xh;  dl = Xl;  j = i;           haslo = true; }
    else if (i < NX + NW) { src = Wqkv; dh = Wqh; dl = Wql; j = i - NX;      haslo = true; }
    else                  { src = Wout; dh = Wo;  dl = Wo;  j = i - NX - NW; haslo = false; }
    f32x4 v = *(const f32x4*)&src[(size_t)j * 4];
    bf16x4 h4, l4;
#pragma unroll
    for (int r = 0; r < 4; ++r) {
      bf16 h = (bf16)v[r]; h4[r] = h; l4[r] = (bf16)(v[r] - (float)h);
    }
    *(bf16x4*)&dh[(size_t)j * 4] = h4;
    if (haslo) *(bf16x4*)&dl[(size_t)j * 4] = l4;
  }
}

// ---------------------------------------------------------------------------
// QKV projection: pure bf16 hi/lo GEMM on pre-converted inputs. XCD-stripe
// swizzle + XOR-chunk LDS. V-tiles (n0%192==128) skip lo-corrections: V is
// stored bf16 anyway and its error is /2048-suppressed through Vtot.
// ---------------------------------------------------------------------------
__global__ __launch_bounds__(256)
void gemm_qkv(const bf16* __restrict__ Xh, const bf16* __restrict__ Xl,
              const bf16* __restrict__ Wh, const bf16* __restrict__ Wl,
              const float* __restrict__ bias,
              bf16* __restrict__ Qh, bf16* __restrict__ Ql,
              bf16* __restrict__ Kh, bf16* __restrict__ Kl,
              bf16* __restrict__ Vrm) {
  __shared__ __align__(16) bf16 Ah[64][64], Al[64][64];
  __shared__ __align__(16) bf16 Bh[64][64], Bl[64][64];
  const int tid  = threadIdx.x;
  const int lane = tid & 63, wave = tid >> 6;
  const int lin = blockIdx.x + gridDim.x * blockIdx.y;
  const int xcd = lin & 7;
  const int w_  = lin >> 3;                  // 0..383
  const int m0 = ((w_ & 15) + xcd * 16) * 64;
  const int n0 = (w_ >> 4) * 64;
  const bool isV = ((n0 % 192) == 128);      // V third: hi-only suffices
  const int wm = (wave >> 1) * 32, wn = (wave & 1) * 32;
  const int c = lane & 15, quad = lane >> 4;
  const int sr   = tid >> 3;                 // 0..31 staging row
  const int scol = (tid & 7) * 8;
  const int sphy = ((tid & 7) ^ (sr & 7)) * 8;   // (sr+32)&7 == sr&7

  const f32x4 zero = {0.f, 0.f, 0.f, 0.f};
  f32x4 acc[2][2];
  acc[0][0] = zero; acc[0][1] = zero; acc[1][0] = zero; acc[1][1] = zero;

  for (int k0 = 0; k0 < 512; k0 += 64) {
    *(bf16x8*)&Ah[sr][sphy]      = *(const bf16x8*)&Xh[(size_t)(m0 + sr     ) * 512 + k0 + scol];
    *(bf16x8*)&Ah[sr + 32][sphy] = *(const bf16x8*)&Xh[(size_t)(m0 + sr + 32) * 512 + k0 + scol];
    *(bf16x8*)&Bh[sr][sphy]      = *(const bf16x8*)&Wh[(size_t)(n0 + sr     ) * 512 + k0 + scol];
    *(bf16x8*)&Bh[sr + 32][sphy] = *(const bf16x8*)&Wh[(size_t)(n0 + sr + 32) * 512 + k0 + scol];
    if (!isV) {
      *(bf16x8*)&Al[sr][sphy]      = *(const bf16x8*)&Xl[(size_t)(m0 + sr     ) * 512 + k0 + scol];
      *(bf16x8*)&Al[sr + 32][sphy] = *(const bf16x8*)&Xl[(size_t)(m0 + sr + 32) * 512 + k0 + scol];
      *(bf16x8*)&Bl[sr][sphy]      = *(const bf16x8*)&Wl[(size_t)(n0 + sr     ) * 512 + k0 + scol];
      *(bf16x8*)&Bl[sr + 32][sphy] = *(const bf16x8*)&Wl[(size_t)(n0 + sr + 32) * 512 + k0 + scol];
    }
    __syncthreads();
#pragma unroll
    for (int ks = 0; ks < 64; ks += 32) {
      const int px = (((ks >> 3) + quad) ^ (c & 7)) * 8;
      bf16x8 ah0 = *(bf16x8*)&Ah[wm + c     ][px];
      bf16x8 ah1 = *(bf16x8*)&Ah[wm + 16 + c][px];
      bf16x8 bh0 = *(bf16x8*)&Bh[wn + c     ][px];
      bf16x8 bh1 = *(bf16x8*)&Bh[wn + 16 + c][px];
      if (isV) {
        acc[0][0] = MFMA(ah0, bh0, acc[0][0]);
        acc[0][1] = MFMA(ah0, bh1, acc[0][1]);
        acc[1][0] = MFMA(ah1, bh0, acc[1][0]);
        acc[1][1] = MFMA(ah1, bh1, acc[1][1]);
      } else {
        bf16x8 al0 = *(bf16x8*)&Al[wm + c     ][px];
        bf16x8 al1 = *(bf16x8*)&Al[wm + 16 + c][px];
        bf16x8 bl0 = *(bf16x8*)&Bl[wn + c     ][px];
        bf16x8 bl1 = *(bf16x8*)&Bl[wn + 16 + c][px];
        acc[0][0] = MFMA(ah0, bh0, acc[0][0]);
        acc[0][0] = MFMA(al0, bh0, acc[0][0]);
        acc[0][0] = MFMA(ah0, bl0, acc[0][0]);
        acc[0][1] = MFMA(ah0, bh1, acc[0][1]);
        acc[0][1] = MFMA(al0, bh1, acc[0][1]);
        acc[0][1] = MFMA(ah0, bl1, acc[0][1]);
        acc[1][0] = MFMA(ah1, bh0, acc[1][0]);
        acc[1][0] = MFMA(al1, bh0, acc[1][0]);
        acc[1][0] = MFMA(ah1, bl0, acc[1][0]);
        acc[1][1] = MFMA(ah1, bh1, acc[1][1]);
        acc[1][1] = MFMA(al1, bh1, acc[1][1]);
        acc[1][1] = MFMA(ah1, bl1, acc[1][1]);
      }
    }
    __syncthreads();
  }

#pragma unroll
  for (int mt = 0; mt < 2; ++mt) {
#pragma unroll
    for (int nt = 0; nt < 2; ++nt) {
      const int n = n0 + wn + nt * 16 + c;
      const float bv = bias[n];
#pragma unroll
      for (int r = 0; r < 4; ++r) {
        const int m = m0 + wm + mt * 16 + quad * 4 + r;
        float v = acc[mt][nt][r] + bv;
        const int h = n / 192, t = n % 192;
        const size_t bh = (size_t)((m >> 11) * 8 + h);
        const int s = m & 2047;
        if (t < 64) {
          float q = v * SCALE;
          bf16 hi = (bf16)q;
          float lo = q - (float)hi;
          size_t idx = (bh * SEQ + s) * HD + t;
          Qh[idx] = hi; Ql[idx] = (bf16)lo;
        } else if (t < 128) {
          bf16 hi = (bf16)v;
          float lo = v - (float)hi;
          size_t idx = (bh * SEQ + s) * HD + (t - 64);
          Kh[idx] = hi; Kl[idx] = (bf16)lo;
        } else {
          Vrm[(bh * SEQ + s) * HD + (t - 128)] = (bf16)v;
        }
      }
    }
  }
}

// ---------------------------------------------------------------------------
// Output projection: bf16 x bf16 (pre-converted Wo), fp32 out. Same XOR-swz.
// ---------------------------------------------------------------------------
__global__ __launch_bounds__(256)
void gemm_out(const bf16* __restrict__ A, const bf16* __restrict__ Wo,
              const float* __restrict__ bias, float* __restrict__ C) {
  __shared__ __align__(16) bf16 As[64][64];
  __shared__ __align__(16) bf16 Bs[64][64];
  const int tid  = threadIdx.x;
  const int lane = tid & 63, wave = tid >> 6;
  const int lin = blockIdx.x + gridDim.x * blockIdx.y;
  const int xcd = lin & 7;
  const int w_  = lin >> 3;                  // 0..127
  const int m0 = ((w_ & 15) + xcd * 16) * 64;
  const int n0 = (w_ >> 4) * 64;
  const int wm = (wave >> 1) * 32, wn = (wave & 1) * 32;
  const int c = lane & 15, quad = lane >> 4;
  const int sr   = tid >> 3;
  const int scol = (tid & 7) * 8;
  const int sphy = ((tid & 7) ^ (sr & 7)) * 8;

  const f32x4 zero = {0.f, 0.f, 0.f, 0.f};
  f32x4 acc[2][2];
  acc[0][0] = zero; acc[0][1] = zero; acc[1][0] = zero; acc[1][1] = zero;

  for (int k0 = 0; k0 < 512; k0 += 64) {
    *(bf16x8*)&As[sr][sphy]      = *(const bf16x8*)&A [(size_t)(m0 + sr     ) * 512 + k0 + scol];
    *(bf16x8*)&As[sr + 32][sphy] = *(const bf16x8*)&A [(size_t)(m0 + sr + 32) * 512 + k0 + scol];
    *(bf16x8*)&Bs[sr][sphy]      = *(const bf16x8*)&Wo[(size_t)(n0 + sr     ) * 512 + k0 + scol];
    *(bf16x8*)&Bs[sr + 32][sphy] = *(const bf16x8*)&Wo[(size_t)(n0 + sr + 32) * 512 + k0 + scol];
    __syncthreads();
#pragma unroll
    for (int ks = 0; ks < 64; ks += 32) {
      const int px = (((ks >> 3) + quad) ^ (c & 7)) * 8;
      bf16x8 a0 = *(bf16x8*)&As[wm + c     ][px];
      bf16x8 a1 = *(bf16x8*)&As[wm + 16 + c][px];
      bf16x8 b0 = *(bf16x8*)&Bs[wn + c     ][px];
      bf16x8 b1 = *(bf16x8*)&Bs[wn + 16 + c][px];
      acc[0][0] = MFMA(a0, b0, acc[0][0]);
      acc[0][1] = MFMA(a0, b1, acc[0][1]);
      acc[1][0] = MFMA(a1, b0, acc[1][0]);
      acc[1][1] = MFMA(a1, b1, acc[1][1]);
    }
    __syncthreads();
  }

#pragma unroll
  for (int mt = 0; mt < 2; ++mt) {
#pragma unroll
    for (int nt = 0; nt < 2; ++nt) {
      const int n = n0 + wn + nt * 16 + c;
      const float bv = bias[n];
#pragma unroll
      for (int r = 0; r < 4; ++r) {
        const int m = m0 + wm + mt * 16 + quad * 4 + r;
        C[(size_t)m * 512 + n] = acc[mt][nt][r] + bv;
      }
    }
  }
}

// ---------------------------------------------------------------------------
// Per-head V column partial sums: Vp[pc][bh][d] = sum_{s in chunk pc} V[s][d].
// ---------------------------------------------------------------------------
__global__ __launch_bounds__(256)
void vsum_kernel(const bf16* __restrict__ Vrm, float* __restrict__ Vp) {
  __shared__ float red[32][64];
  const int pc = blockIdx.x >> 5;
  const int bh = blockIdx.x & 31;
  const bf16* p = Vrm + ((size_t)bh * SEQ + pc * 256) * HD;
  const int g  = threadIdx.x >> 3;
  const int dc = (threadIdx.x & 7) * 8;
  float s[8] = {0.f,0.f,0.f,0.f,0.f,0.f,0.f,0.f};
  for (int s0 = g; s0 < 256; s0 += 32) {
    bf16x8 v = *(const bf16x8*)&p[(size_t)s0 * HD + dc];
#pragma unroll
    for (int j = 0; j < 8; ++j) s[j] += (float)v[j];
  }
#pragma unroll
  for (int j = 0; j < 8; ++j) red[g][dc + j] = s[j];
  __syncthreads();
  if (threadIdx.x < 64) {
    float a = 0.f;
#pragma unroll
    for (int g2 = 0; g2 < 32; ++g2) a += red[g2][threadIdx.x];
    Vp[(size_t)(pc * 32 + bh) * 64 + threadIdx.x] = a;
  }
}

// ---------------------------------------------------------------------------
// Attention, double softmax, shift-invariant form. Round-5 restructure:
//   SCAN (staged, 16 barriers): hi-only s~, per-query shift mq, tile maxes.
//   MASK: per-wave 128-bit active-tile bitmask via ballot (gate identical to
//         round 4: cms~ > mq-28). No barriers after SCAN at all.
//   B:    barrier-free dense iteration over ACTIVE tiles only (~25/128),
//         2-deep software-pipelined, Kh/Kl rows read direct from global
//         (L2-resident; same bits the LDS path delivered -> same numerics).
//   C:    per-query key-list finish (exp(p/l1)-1, V-row gather), unchanged.
// ---------------------------------------------------------------------------
__global__ __launch_bounds__(512, 4)
void attn_kernel(const bf16* __restrict__ Qh, const bf16* __restrict__ Ql,
                 const bf16* __restrict__ Kh, const bf16* __restrict__ Kl,
                 const bf16* __restrict__ Vrm, const float* __restrict__ Vp,
                 bf16* __restrict__ O) {
  __shared__ __align__(16) char pool[32768];     // Kh stage [2][128][64] bf16
  __shared__ unsigned char cms8[8][128][16];     // per-wave tile-max (s~/8+128)
  __shared__ float plistP[8][16][16];            // per-query p list
  __shared__ unsigned short plistI[8][16][16];   // per-query key-idx list
  __shared__ int pcnt[8][16];
  __shared__ float mqs[8][16];                   // per-query shift broadcast
  bf16 (*SK)[64] = (bf16(*)[64])pool;

  const int tid  = threadIdx.x;
  const int lane = tid & 63, wave = tid >> 6;
  const int c = lane & 15, quad = lane >> 4;
  const int bh = blockIdx.x;
  const int q0 = blockIdx.y * 128 + wave * 16;
  const size_t hoff = (size_t)bh * SEQ * HD;
  const bf16* qh_p = Qh + hoff;
  const bf16* ql_p = Ql + hoff;
  const bf16* kh_p = Kh + hoff;
  const bf16* kl_p = Kl + hoff;
  const bf16* v_p  = Vrm + hoff;
  const f32x4 zero = {0.f, 0.f, 0.f, 0.f};

  const int sr   = tid >> 3;                     // 0..63 staging row
  const int scol = (tid & 7) * 8;
  const int sphy = ((tid & 7) ^ (sr & 7)) * 8;
  const int pc0  = ((0 + quad) ^ (c & 7)) * 8;
  const int pc1  = ((4 + quad) ^ (c & 7)) * 8;

  bf16x8 qf[2], qlf[2];
#pragma unroll
  for (int t = 0; t < 2; ++t) {
    size_t off = (size_t)(q0 + c) * HD + t * 32 + quad * 8;
    qf[t]  = *(const bf16x8*)&qh_p[off];
    qlf[t] = *(const bf16x8*)&ql_p[off];
  }

  // ====================== phase SCAN: hi-only s~ (staged) ==================
  bf16x8 pA = *(const bf16x8*)&kh_p[(size_t)sr * HD + scol];
  bf16x8 pB = *(const bf16x8*)&kh_p[(size_t)(sr + 64) * HD + scol];
  *(bf16x8*)&SK[sr][sphy]      = pA;
  *(bf16x8*)&SK[sr + 64][sphy] = pB;
  __syncthreads();
  int buf = 0;
  float mqL = NEG_SEED;
  for (int cs = 0; cs < 16; ++cs) {
    if (cs < 15) {
      const size_t k0 = (size_t)(cs + 1) * 128;
      pA = *(const bf16x8*)&kh_p[(k0 + sr) * HD + scol];
      pB = *(const bf16x8*)&kh_p[(k0 + sr + 64) * HD + scol];
    }
#pragma unroll
    for (int t = 0; t < 8; ++t) {
      bf16x8 k0 = *(bf16x8*)&SK[buf * 128 + t * 16 + c][pc0];
      bf16x8 k1 = *(bf16x8*)&SK[buf * 128 + t * 16 + c][pc1];
      f32x4 sc = MFMA(k0, qf[0], zero);
      sc = MFMA(k1, qf[1], sc);
      float cm = fmaxf(fmaxf(sc[0], sc[1]), fmaxf(sc[2], sc[3]));
      mqL = fmaxf(mqL, cm);
      float c2 = fmaxf(cm, __shfl_xor(cm, 16, 64));
      c2 = fmaxf(c2, __shfl_xor(c2, 32, 64));
      if (quad == 0) {
        int qv = (int)(c2 * 0.125f + 128.5f);
        qv = qv < 0 ? 0 : (qv > 255 ? 255 : qv);
        cms8[wave][cs * 8 + t][c] = (unsigned char)qv;
      }
    }
    if (cs < 15) {
      const int nb = buf ^ 1;
      *(bf16x8*)&SK[nb * 128 + sr][sphy]      = pA;
      *(bf16x8*)&SK[nb * 128 + sr + 64][sphy] = pB;
      __syncthreads();
      buf = nb;
    }
  }
  // per-query shift (hi-only max; any shift is exact by shift-invariance)
  float mq = fmaxf(mqL, __shfl_xor(mqL, 16, 64));
  mq = fmaxf(mq, __shfl_xor(mq, 32, 64));

  // ============ MASK: per-wave active-tile bitmask (no barriers) ===========
  if (quad == 0) mqs[wave][c] = mq;   // same-wave write->read, LDS in-order
  if (lane < 16) pcnt[wave][lane] = 0;
  bool pr0 = false, pr1 = false;
#pragma unroll
  for (int cc = 0; cc < 16; ++cc) {
    const float th = mqs[wave][cc] - 28.f;
    pr0 |= ((float)((int)cms8[wave][lane     ][cc] - 128) * 8.0f) > th;
    pr1 |= ((float)((int)cms8[wave][lane + 64][cc] - 128) * 8.0f) > th;
  }
  unsigned long long a0 = __ballot(pr0);
  unsigned long long a1 = __ballot(pr1);

  // ====== phase B: dense active tiles, barrier-free, 2-deep pipeline =======
  float l1 = 0.f;

#define POPG(dst) do { \
    if (a0) { dst = __builtin_ctzll(a0); a0 &= a0 - 1; } \
    else if (a1) { dst = 64 + __builtin_ctzll(a1); a1 &= a1 - 1; } \
    else dst = -1; } while (0)

#define LOADK(g, K0, K1, K2, K3) do { \
    const size_t kr_ = (size_t)((g) * 16 + c) * HD + quad * 8; \
    K0 = *(const bf16x8*)&kh_p[kr_]; \
    K1 = *(const bf16x8*)&kh_p[kr_ + 32]; \
    K2 = *(const bf16x8*)&kl_p[kr_]; \
    K3 = *(const bf16x8*)&kl_p[kr_ + 32]; } while (0)

#define PROC_TILE(g, K0, K1, K2, K3) do { \
    f32x4 sc_ = MFMA(K0, qf[0], zero); \
    sc_ = MFMA(K0, qlf[0], sc_); \
    sc_ = MFMA(K1, qf[1],  sc_); \
    sc_ = MFMA(K1, qlf[1], sc_); \
    sc_ = MFMA(K2, qf[0],  sc_); \
    sc_ = MFMA(K3, qf[1],  sc_); \
    for (int r_ = 0; r_ < 4; ++r_) { \
      const float d_ = sc_[r_] - mq; \
      const float p_ = __expf(d_); \
      l1 += p_; \
      if (d_ > -16.f) { \
        const int slot_ = atomicAdd(&pcnt[wave][c], 1); \
        if (slot_ < 16) { \
          plistP[wave][c][slot_] = p_; \
          plistI[wave][c][slot_] = (unsigned short)((g) * 16 + quad * 4 + r_); \
        } \
      } \
    } } while (0)

  {
    int gA, gB;
    bf16x8 A0{}, A1{}, A2{}, A3{}, B0{}, B1{}, B2{}, B3{};
    POPG(gA);
    if (gA >= 0) LOADK(gA, A0, A1, A2, A3);
    while (gA >= 0) {
      POPG(gB);
      if (gB >= 0) LOADK(gB, B0, B1, B2, B3);
      PROC_TILE(gA, A0, A1, A2, A3);
      if (gB < 0) break;
      POPG(gA);
      if (gA >= 0) LOADK(gA, A0, A1, A2, A3);
      PROC_TILE(gB, B0, B1, B2, B3);
    }
  }
  l1 += __shfl_xor(l1, 16, 64);
  l1 += __shfl_xor(l1, 32, 64);

  // ====================== phase C: finish (per-wave, tiny) =================
  const float inv1 = 1.f / l1;
  float oc[16];
#pragma unroll
  for (int i = 0; i < 16; ++i) oc[i] = 0.f;
  float l2 = 0.f;
  const int n = min(pcnt[wave][c], 16);
  for (int j = 0; j < n; ++j) {
    const float a1v = plistP[wave][c][j] * inv1;  // attn1 in [0,1]
    const int  idx = plistI[wave][c][j];
    const float t1 = __expf(a1v) - 1.0f;          // t-1
    l2 += t1;
    const bf16* vp = &v_p[(size_t)idx * HD + quad * 4];
#pragma unroll
    for (int dt = 0; dt < 4; ++dt) {
      bf16x4 v4 = *(const bf16x4*)&vp[dt * 16];
#pragma unroll
      for (int r = 0; r < 4; ++r) oc[dt * 4 + r] += t1 * (float)v4[r];
    }
  }

  const int b = bh >> 3, h = bh & 7;
  const float rcp = 1.f / (2048.f + l2);
  const float* vpp = Vp + (size_t)bh * HD;       // partial chunks stride 32*64
  bf16* orow = &O[((size_t)b * SEQ + q0 + c) * EMB + h * HD];
#pragma unroll
  for (int dt = 0; dt < 4; ++dt) {
    f32x4 vt4 = zero;
#pragma unroll
    for (int pc = 0; pc < 8; ++pc)
      vt4 += *(const f32x4*)&vpp[(size_t)pc * 32 * 64 + dt * 16 + quad * 4];
    bf16x4 ov;
#pragma unroll
    for (int r = 0; r < 4; ++r) ov[r] = (bf16)((oc[dt * 4 + r] + vt4[r]) * rcp);
    *(bf16x4*)&orow[dt * 16 + quad * 4] = ov;
  }
}

// ---------------------------------------------------------------------------
extern "C" void kernel_launch(void* const* d_in, const int* in_sizes, int n_in,
                              void* d_out, int out_size, void* d_ws, size_t ws_size,
                              hipStream_t stream) {
  const float* x    = (const float*)d_in[0];
  const float* Wqkv = (const float*)d_in[1];
  const float* bqkv = (const float*)d_in[2];
  const float* Wout = (const float*)d_in[3];
  const float* bout = (const float*)d_in[4];
  float* out = (float*)d_out;

  char* ws = (char*)d_ws;
  const size_t SZ = (size_t)32 * SEQ * HD * 2;  // 8 MiB per array
  bf16* Qh  = (bf16*)(ws + 0 * SZ);
  bf16* Ql  = (bf16*)(ws + 1 * SZ);
  bf16* Kh  = (bf16*)(ws + 2 * SZ);
  bf16* Kl  = (bf16*)(ws + 3 * SZ);
  bf16* Vrm = (bf16*)(ws + 4 * SZ);
  bf16* XhO = (bf16*)(ws + 5 * SZ);  // Xh during proj; overwritten by O in attn
  bf16* Xl  = (bf16*)(ws + 6 * SZ);
  bf16* Wqh = (bf16*)(ws + 7 * SZ);
  bf16* Wql = (bf16*)(ws + 7 * SZ + 0x180000);
  bf16* Wo  = (bf16*)(ws + 7 * SZ + 0x300000);
  float* Vp = (float*)(ws + 7 * SZ + 0x380000);  // 8x32x64 f32 partials

  convert_kernel<<<dim3(2048), 256, 0, stream>>>(x, Wqkv, Wout, XhO, Xl, Wqh, Wql, Wo);
  gemm_qkv<<<dim3(128, 24), 256, 0, stream>>>(XhO, Xl, Wqh, Wql, bqkv, Qh, Ql, Kh, Kl, Vrm);
  vsum_kernel<<<dim3(256), 256, 0, stream>>>(Vrm, Vp);
  attn_kernel<<<dim3(32, SEQ / 128), 512, 0, stream>>>(Qh, Ql, Kh, Kl, Vrm, Vp, XhO);
  gemm_out<<<dim3(128, 8), 256, 0, stream>>>(XhO, Wo, bout, out);
}

// Round 6
// 217.088 us; speedup vs baseline: 1.0067x; 1.0067x over previous
//
#include <hip/hip_runtime.h>

typedef __bf16 bf16;
typedef __attribute__((ext_vector_type(4))) __bf16 bf16x4;
typedef __attribute__((ext_vector_type(8))) __bf16 bf16x8;
typedef __attribute__((ext_vector_type(4))) float f32x4;

#define MFMA(A,B,C) __builtin_amdgcn_mfma_f32_16x16x32_bf16(A,B,C,0,0,0)

#define SEQ 2048
#define EMB 512
#define HD  64
#define SCALE 22.627416997969522f  // sqrt(512): scores are divided by E^-0.5
// Online-softmax seed: not -inf (fast-math folds inf constants to poison).
#define NEG_SEED -3.0e4f

// ---------------------------------------------------------------------------
// One-shot fp32 -> bf16 hi/lo conversion (x, W_qkv) and bf16 (W_out).
// Also zeroes the Vs accumulator (gemm_qkv atomicAdds into it).
// ---------------------------------------------------------------------------
__global__ __launch_bounds__(256)
void convert_kernel(const float* __restrict__ x, const float* __restrict__ Wqkv,
                    const float* __restrict__ Wout,
                    bf16* __restrict__ Xh, bf16* __restrict__ Xl,
                    bf16* __restrict__ Wqh, bf16* __restrict__ Wql,
                    bf16* __restrict__ Wo, float* __restrict__ Vs) {
  if (blockIdx.x < 8) Vs[blockIdx.x * 256 + threadIdx.x] = 0.f;  // 32*64 floats
  const int NX = 8192 * 512 / 4;   // f32x4 chunks
  const int NW = 1536 * 512 / 4;
  const int NO = 512 * 512 / 4;
  const int stride = gridDim.x * 256;
  for (int i = blockIdx.x * 256 + threadIdx.x; i < NX + NW + NO; i += stride) {
    const float* src; bf16 *dh, *dl; int j; bool haslo;
    if (i < NX)           { src = x;    dh = Xh;  dl = Xl;  j = i;           haslo = true; }
    else if (i < NX + NW) { src = Wqkv; dh = Wqh; dl = Wql; j = i - NX;      haslo = true; }
    else                  { src = Wout; dh = Wo;  dl = Wo;  j = i - NX - NW; haslo = false; }
    f32x4 v = *(const f32x4*)&src[(size_t)j * 4];
    bf16x4 h4, l4;
#pragma unroll
    for (int r = 0; r < 4; ++r) {
      bf16 h = (bf16)v[r]; h4[r] = h; l4[r] = (bf16)(v[r] - (float)h);
    }
    *(bf16x4*)&dh[(size_t)j * 4] = h4;
    if (haslo) *(bf16x4*)&dl[(size_t)j * 4] = l4;
  }
}

// ---------------------------------------------------------------------------
// QKV projection: bf16 hi/lo GEMM on pre-converted inputs. XCD-stripe swizzle
// + XOR-chunk LDS. V-tiles (n0%192==128) are hi-only AND fuse the per-head
// V column sums (Vtot) via fp32 atomics -> vsum kernel eliminated.
// ---------------------------------------------------------------------------
__global__ __launch_bounds__(256)
void gemm_qkv(const bf16* __restrict__ Xh, const bf16* __restrict__ Xl,
              const bf16* __restrict__ Wh, const bf16* __restrict__ Wl,
              const float* __restrict__ bias,
              bf16* __restrict__ Qh, bf16* __restrict__ Ql,
              bf16* __restrict__ Kh, bf16* __restrict__ Kl,
              bf16* __restrict__ Vrm, float* __restrict__ Vs) {
  __shared__ __align__(16) bf16 Ah[64][64], Al[64][64];
  __shared__ __align__(16) bf16 Bh[64][64], Bl[64][64];
  const int tid  = threadIdx.x;
  const int lane = tid & 63, wave = tid >> 6;
  const int lin = blockIdx.x + gridDim.x * blockIdx.y;
  const int xcd = lin & 7;
  const int w_  = lin >> 3;                  // 0..383
  const int m0 = ((w_ & 15) + xcd * 16) * 64;
  const int n0 = (w_ >> 4) * 64;
  const bool isV = ((n0 % 192) == 128);      // V third: hi-only suffices
  const int wm = (wave >> 1) * 32, wn = (wave & 1) * 32;
  const int c = lane & 15, quad = lane >> 4;
  const int sr   = tid >> 3;                 // 0..31 staging row
  const int scol = (tid & 7) * 8;
  const int sphy = ((tid & 7) ^ (sr & 7)) * 8;   // (sr+32)&7 == sr&7

  const f32x4 zero = {0.f, 0.f, 0.f, 0.f};
  f32x4 acc[2][2];
  acc[0][0] = zero; acc[0][1] = zero; acc[1][0] = zero; acc[1][1] = zero;

  for (int k0 = 0; k0 < 512; k0 += 64) {
    *(bf16x8*)&Ah[sr][sphy]      = *(const bf16x8*)&Xh[(size_t)(m0 + sr     ) * 512 + k0 + scol];
    *(bf16x8*)&Ah[sr + 32][sphy] = *(const bf16x8*)&Xh[(size_t)(m0 + sr + 32) * 512 + k0 + scol];
    *(bf16x8*)&Bh[sr][sphy]      = *(const bf16x8*)&Wh[(size_t)(n0 + sr     ) * 512 + k0 + scol];
    *(bf16x8*)&Bh[sr + 32][sphy] = *(const bf16x8*)&Wh[(size_t)(n0 + sr + 32) * 512 + k0 + scol];
    if (!isV) {
      *(bf16x8*)&Al[sr][sphy]      = *(const bf16x8*)&Xl[(size_t)(m0 + sr     ) * 512 + k0 + scol];
      *(bf16x8*)&Al[sr + 32][sphy] = *(const bf16x8*)&Xl[(size_t)(m0 + sr + 32) * 512 + k0 + scol];
      *(bf16x8*)&Bl[sr][sphy]      = *(const bf16x8*)&Wl[(size_t)(n0 + sr     ) * 512 + k0 + scol];
      *(bf16x8*)&Bl[sr + 32][sphy] = *(const bf16x8*)&Wl[(size_t)(n0 + sr + 32) * 512 + k0 + scol];
    }
    __syncthreads();
#pragma unroll
    for (int ks = 0; ks < 64; ks += 32) {
      const int px = (((ks >> 3) + quad) ^ (c & 7)) * 8;
      bf16x8 ah0 = *(bf16x8*)&Ah[wm + c     ][px];
      bf16x8 ah1 = *(bf16x8*)&Ah[wm + 16 + c][px];
      bf16x8 bh0 = *(bf16x8*)&Bh[wn + c     ][px];
      bf16x8 bh1 = *(bf16x8*)&Bh[wn + 16 + c][px];
      if (isV) {
        acc[0][0] = MFMA(ah0, bh0, acc[0][0]);
        acc[0][1] = MFMA(ah0, bh1, acc[0][1]);
        acc[1][0] = MFMA(ah1, bh0, acc[1][0]);
        acc[1][1] = MFMA(ah1, bh1, acc[1][1]);
      } else {
        bf16x8 al0 = *(bf16x8*)&Al[wm + c     ][px];
        bf16x8 al1 = *(bf16x8*)&Al[wm + 16 + c][px];
        bf16x8 bl0 = *(bf16x8*)&Bl[wn + c     ][px];
        bf16x8 bl1 = *(bf16x8*)&Bl[wn + 16 + c][px];
        acc[0][0] = MFMA(ah0, bh0, acc[0][0]);
        acc[0][0] = MFMA(al0, bh0, acc[0][0]);
        acc[0][0] = MFMA(ah0, bl0, acc[0][0]);
        acc[0][1] = MFMA(ah0, bh1, acc[0][1]);
        acc[0][1] = MFMA(al0, bh1, acc[0][1]);
        acc[0][1] = MFMA(ah0, bl1, acc[0][1]);
        acc[1][0] = MFMA(ah1, bh0, acc[1][0]);
        acc[1][0] = MFMA(al1, bh0, acc[1][0]);
        acc[1][0] = MFMA(ah1, bl0, acc[1][0]);
        acc[1][1] = MFMA(ah1, bh1, acc[1][1]);
        acc[1][1] = MFMA(al1, bh1, acc[1][1]);
        acc[1][1] = MFMA(ah1, bl1, acc[1][1]);
      }
    }
    __syncthreads();
  }

  if (isV) {
    // V epilogue: store bf16 V rows and fuse Vtot column sums (fp32 atomics).
#pragma unroll
    for (int nt = 0; nt < 2; ++nt) {
      const int n = n0 + wn + nt * 16 + c;
      const float bv = bias[n];
      const int h = n / 192, d = n % 192 - 128;
      const size_t bh = (size_t)((m0 >> 11) * 8 + h);
      float csum = 0.f;
#pragma unroll
      for (int mt = 0; mt < 2; ++mt)
#pragma unroll
        for (int r = 0; r < 4; ++r) {
          const int m = m0 + wm + mt * 16 + quad * 4 + r;
          const int s = m & 2047;
          float v = acc[mt][nt][r] + bv;
          Vrm[(bh * SEQ + s) * HD + d] = (bf16)v;
          csum += v;
        }
      csum += __shfl_xor(csum, 16, 64);
      csum += __shfl_xor(csum, 32, 64);
      if (quad == 0) atomicAdd(&Vs[bh * HD + d], csum);
    }
  } else {
#pragma unroll
    for (int mt = 0; mt < 2; ++mt) {
#pragma unroll
      for (int nt = 0; nt < 2; ++nt) {
        const int n = n0 + wn + nt * 16 + c;
        const float bv = bias[n];
#pragma unroll
        for (int r = 0; r < 4; ++r) {
          const int m = m0 + wm + mt * 16 + quad * 4 + r;
          float v = acc[mt][nt][r] + bv;
          const int h = n / 192, t = n % 192;
          const size_t bh = (size_t)((m >> 11) * 8 + h);
          const int s = m & 2047;
          if (t < 64) {
            float q = v * SCALE;
            bf16 hi = (bf16)q;
            float lo = q - (float)hi;
            size_t idx = (bh * SEQ + s) * HD + t;
            Qh[idx] = hi; Ql[idx] = (bf16)lo;
          } else {
            bf16 hi = (bf16)v;
            float lo = v - (float)hi;
            size_t idx = (bh * SEQ + s) * HD + (t - 64);
            Kh[idx] = hi; Kl[idx] = (bf16)lo;
          }
        }
      }
    }
  }
}

// ---------------------------------------------------------------------------
// Output projection: bf16 x bf16 (pre-converted Wo), fp32 out. Same XOR-swz.
// ---------------------------------------------------------------------------
__global__ __launch_bounds__(256)
void gemm_out(const bf16* __restrict__ A, const bf16* __restrict__ Wo,
              const float* __restrict__ bias, float* __restrict__ C) {
  __shared__ __align__(16) bf16 As[64][64];
  __shared__ __align__(16) bf16 Bs[64][64];
  const int tid  = threadIdx.x;
  const int lane = tid & 63, wave = tid >> 6;
  const int lin = blockIdx.x + gridDim.x * blockIdx.y;
  const int xcd = lin & 7;
  const int w_  = lin >> 3;                  // 0..127
  const int m0 = ((w_ & 15) + xcd * 16) * 64;
  const int n0 = (w_ >> 4) * 64;
  const int wm = (wave >> 1) * 32, wn = (wave & 1) * 32;
  const int c = lane & 15, quad = lane >> 4;
  const int sr   = tid >> 3;
  const int scol = (tid & 7) * 8;
  const int sphy = ((tid & 7) ^ (sr & 7)) * 8;

  const f32x4 zero = {0.f, 0.f, 0.f, 0.f};
  f32x4 acc[2][2];
  acc[0][0] = zero; acc[0][1] = zero; acc[1][0] = zero; acc[1][1] = zero;

  for (int k0 = 0; k0 < 512; k0 += 64) {
    *(bf16x8*)&As[sr][sphy]      = *(const bf16x8*)&A [(size_t)(m0 + sr     ) * 512 + k0 + scol];
    *(bf16x8*)&As[sr + 32][sphy] = *(const bf16x8*)&A [(size_t)(m0 + sr + 32) * 512 + k0 + scol];
    *(bf16x8*)&Bs[sr][sphy]      = *(const bf16x8*)&Wo[(size_t)(n0 + sr     ) * 512 + k0 + scol];
    *(bf16x8*)&Bs[sr + 32][sphy] = *(const bf16x8*)&Wo[(size_t)(n0 + sr + 32) * 512 + k0 + scol];
    __syncthreads();
#pragma unroll
    for (int ks = 0; ks < 64; ks += 32) {
      const int px = (((ks >> 3) + quad) ^ (c & 7)) * 8;
      bf16x8 a0 = *(bf16x8*)&As[wm + c     ][px];
      bf16x8 a1 = *(bf16x8*)&As[wm + 16 + c][px];
      bf16x8 b0 = *(bf16x8*)&Bs[wn + c     ][px];
      bf16x8 b1 = *(bf16x8*)&Bs[wn + 16 + c][px];
      acc[0][0] = MFMA(a0, b0, acc[0][0]);
      acc[0][1] = MFMA(a0, b1, acc[0][1]);
      acc[1][0] = MFMA(a1, b0, acc[1][0]);
      acc[1][1] = MFMA(a1, b1, acc[1][1]);
    }
    __syncthreads();
  }

#pragma unroll
  for (int mt = 0; mt < 2; ++mt) {
#pragma unroll
    for (int nt = 0; nt < 2; ++nt) {
      const int n = n0 + wn + nt * 16 + c;
      const float bv = bias[n];
#pragma unroll
      for (int r = 0; r < 4; ++r) {
        const int m = m0 + wm + mt * 16 + quad * 4 + r;
        C[(size_t)m * 512 + n] = acc[mt][nt][r] + bv;
      }
    }
  }
}

// ---------------------------------------------------------------------------
// Attention, double softmax, SINGLE staged pass (merged scan+exact):
// Per staged tile: 2 hi-MFMA scan -> tile max tm. Gate __any(tm > mq-31)
// (running per-query mq, conservative). Active: +4 MFMA seeded on the scan
// accumulator (kh in regs, kl from global = round-4's proven in-loop read),
// online mq/l1 with rescale, push raw scores s with s-mq > -16 (late mq
// growth makes stale entries exp(tiny)=1.0f -> t-1 = 0 exactly: harmless).
// Phase C: t-1 = exp(exp(s-mq)/l1)-1, V-row gather. O = Vtot + sum (t-1)V.
// 256 thr / 4 waves, grid (32,32): LDS 39.2KB -> 4 blocks/CU.
// ---------------------------------------------------------------------------
__global__ __launch_bounds__(256, 4)
void attn_kernel(const bf16* __restrict__ Qh, const bf16* __restrict__ Ql,
                 const bf16* __restrict__ Kh, const bf16* __restrict__ Kl,
                 const bf16* __restrict__ Vrm, const float* __restrict__ Vs,
                 bf16* __restrict__ O) {
  __shared__ __align__(16) bf16 SK[2][128][64];   // Kh stage, XOR-chunk swz
  __shared__ float plistS[4][16][16];             // per-query raw-score list
  __shared__ unsigned short plistI[4][16][16];    // per-query key-idx list
  __shared__ int pcnt[4][16];

  const int tid  = threadIdx.x;
  const int lane = tid & 63, wave = tid >> 6;
  const int c = lane & 15, quad = lane >> 4;
  const int bh = blockIdx.x;
  const int q0 = blockIdx.y * 64 + wave * 16;
  const size_t hoff = (size_t)bh * SEQ * HD;
  const bf16* qh_p = Qh + hoff;
  const bf16* ql_p = Ql + hoff;
  const bf16* kh_p = Kh + hoff;
  const bf16* kl_p = Kl + hoff;
  const bf16* v_p  = Vrm + hoff;
  const f32x4 zero = {0.f, 0.f, 0.f, 0.f};

  const int sr   = tid >> 3;                      // 0..31 staging row
  const int scol = (tid & 7) * 8;
  const int sphy = ((tid & 7) ^ (sr & 7)) * 8;
  const int pc0  = ((0 + quad) ^ (c & 7)) * 8;
  const int pc1  = ((4 + quad) ^ (c & 7)) * 8;

  bf16x8 qf[2], qlf[2];
#pragma unroll
  for (int t = 0; t < 2; ++t) {
    size_t off = (size_t)(q0 + c) * HD + t * 32 + quad * 8;
    qf[t]  = *(const bf16x8*)&qh_p[off];
    qlf[t] = *(const bf16x8*)&ql_p[off];
  }
  if (lane < 16) pcnt[wave][lane] = 0;   // same-wave use only

  // prologue: stage chunk 0 (rows sr, +32, +64, +96)
  bf16x8 pA = *(const bf16x8*)&kh_p[(size_t)(sr     ) * HD + scol];
  bf16x8 pB = *(const bf16x8*)&kh_p[(size_t)(sr + 32) * HD + scol];
  bf16x8 pC = *(const bf16x8*)&kh_p[(size_t)(sr + 64) * HD + scol];
  bf16x8 pD = *(const bf16x8*)&kh_p[(size_t)(sr + 96) * HD + scol];
  *(bf16x8*)&SK[0][sr     ][sphy] = pA;
  *(bf16x8*)&SK[0][sr + 32][sphy] = pB;
  *(bf16x8*)&SK[0][sr + 64][sphy] = pC;
  *(bf16x8*)&SK[0][sr + 96][sphy] = pD;
  __syncthreads();

  float mq = NEG_SEED, l1 = 0.f;
  int buf = 0;
  for (int cs = 0; cs < 16; ++cs) {
    if (cs < 15) {
      const size_t k0 = (size_t)(cs + 1) * 128;
      pA = *(const bf16x8*)&kh_p[(k0 + sr     ) * HD + scol];
      pB = *(const bf16x8*)&kh_p[(k0 + sr + 32) * HD + scol];
      pC = *(const bf16x8*)&kh_p[(k0 + sr + 64) * HD + scol];
      pD = *(const bf16x8*)&kh_p[(k0 + sr + 96) * HD + scol];
    }
#pragma unroll
    for (int t = 0; t < 8; ++t) {
      const int g = cs * 8 + t;
      bf16x8 kh0 = *(bf16x8*)&SK[buf][t * 16 + c][pc0];
      bf16x8 kh1 = *(bf16x8*)&SK[buf][t * 16 + c][pc1];
      f32x4 sc = MFMA(kh0, qf[0], zero);
      sc = MFMA(kh1, qf[1], sc);
      const float tm = fmaxf(fmaxf(sc[0], sc[1]), fmaxf(sc[2], sc[3]));
      if (__any(tm > mq - 31.f)) {
        const size_t kr = (size_t)(g * 16 + c) * HD + quad * 8;
        bf16x8 kl0 = *(const bf16x8*)&kl_p[kr];
        bf16x8 kl1 = *(const bf16x8*)&kl_p[kr + 32];
        sc = MFMA(kh0, qlf[0], sc);
        sc = MFMA(kh1, qlf[1], sc);
        sc = MFMA(kl0, qf[0],  sc);
        sc = MFMA(kl1, qf[1],  sc);
        float tme = fmaxf(fmaxf(sc[0], sc[1]), fmaxf(sc[2], sc[3]));
        tme = fmaxf(tme, __shfl_xor(tme, 16, 64));
        tme = fmaxf(tme, __shfl_xor(tme, 32, 64));
        if (tme > mq) {                    // rare: rescale partial l1
          l1 *= __expf(mq - tme);
          mq = tme;
        }
#pragma unroll
        for (int r = 0; r < 4; ++r) {
          const float d = sc[r] - mq;
          l1 += __expf(d);
          if (d > -16.f) {
            const int slot = atomicAdd(&pcnt[wave][c], 1);
            if (slot < 16) {
              plistS[wave][c][slot] = sc[r];
              plistI[wave][c][slot] = (unsigned short)(g * 16 + quad * 4 + r);
            }
          }
        }
      }
    }
    if (cs < 15) {
      const int nb = buf ^ 1;
      *(bf16x8*)&SK[nb][sr     ][sphy] = pA;
      *(bf16x8*)&SK[nb][sr + 32][sphy] = pB;
      *(bf16x8*)&SK[nb][sr + 64][sphy] = pC;
      *(bf16x8*)&SK[nb][sr + 96][sphy] = pD;
      __syncthreads();
      buf = nb;
    }
  }
  // combine quad partials (all 4 lanes of a c-group share the same mq shift)
  l1 += __shfl_xor(l1, 16, 64);
  l1 += __shfl_xor(l1, 32, 64);

  // ====================== phase C: finish (per-wave, tiny) =================
  const float inv1 = 1.f / l1;
  float oc[16];
#pragma unroll
  for (int i = 0; i < 16; ++i) oc[i] = 0.f;
  float l2 = 0.f;
  const int n = min(pcnt[wave][c], 16);
  for (int j = 0; j < n; ++j) {
    const float sv = plistS[wave][c][j];
    const int  idx = plistI[wave][c][j];
    const float a1v = __expf(sv - mq) * inv1;  // attn1 in [0,1]
    const float t1 = __expf(a1v) - 1.0f;       // t-1 (0 exactly for stale)
    l2 += t1;
    const bf16* vp = &v_p[(size_t)idx * HD + quad * 4];
#pragma unroll
    for (int dt = 0; dt < 4; ++dt) {
      bf16x4 v4 = *(const bf16x4*)&vp[dt * 16];
#pragma unroll
      for (int r = 0; r < 4; ++r) oc[dt * 4 + r] += t1 * (float)v4[r];
    }
  }

  const int b = bh >> 3, h = bh & 7;
  const float rcp = 1.f / (2048.f + l2);
  const float* vsp = Vs + bh * HD;
  bf16* orow = &O[((size_t)b * SEQ + q0 + c) * EMB + h * HD];
#pragma unroll
  for (int dt = 0; dt < 4; ++dt) {
    f32x4 vt4 = *(const f32x4*)&vsp[dt * 16 + quad * 4];
    bf16x4 ov;
#pragma unroll
    for (int r = 0; r < 4; ++r) ov[r] = (bf16)((oc[dt * 4 + r] + vt4[r]) * rcp);
    *(bf16x4*)&orow[dt * 16 + quad * 4] = ov;
  }
}

// ---------------------------------------------------------------------------
extern "C" void kernel_launch(void* const* d_in, const int* in_sizes, int n_in,
                              void* d_out, int out_size, void* d_ws, size_t ws_size,
                              hipStream_t stream) {
  const float* x    = (const float*)d_in[0];
  const float* Wqkv = (const float*)d_in[1];
  const float* bqkv = (const float*)d_in[2];
  const float* Wout = (const float*)d_in[3];
  const float* bout = (const float*)d_in[4];
  float* out = (float*)d_out;

  char* ws = (char*)d_ws;
  const size_t SZ = (size_t)32 * SEQ * HD * 2;  // 8 MiB per array
  bf16* Qh  = (bf16*)(ws + 0 * SZ);
  bf16* Ql  = (bf16*)(ws + 1 * SZ);
  bf16* Kh  = (bf16*)(ws + 2 * SZ);
  bf16* Kl  = (bf16*)(ws + 3 * SZ);
  bf16* Vrm = (bf16*)(ws + 4 * SZ);
  bf16* XhO = (bf16*)(ws + 5 * SZ);  // Xh during proj; overwritten by O in attn
  bf16* Xl  = (bf16*)(ws + 6 * SZ);
  bf16* Wqh = (bf16*)(ws + 7 * SZ);
  bf16* Wql = (bf16*)(ws + 7 * SZ + 0x180000);
  bf16* Wo  = (bf16*)(ws + 7 * SZ + 0x300000);
  float* Vs = (float*)(ws + 7 * SZ + 0x380000);  // 32x64 f32 Vtot (atomics)

  convert_kernel<<<dim3(2048), 256, 0, stream>>>(x, Wqkv, Wout, XhO, Xl, Wqh, Wql, Wo, Vs);
  gemm_qkv<<<dim3(128, 24), 256, 0, stream>>>(XhO, Xl, Wqh, Wql, bqkv, Qh, Ql, Kh, Kl, Vrm, Vs);
  attn_kernel<<<dim3(32, 32), 256, 0, stream>>>(Qh, Ql, Kh, Kl, Vrm, Vs, XhO);
  gemm_out<<<dim3(128, 8), 256, 0, stream>>>(XhO, Wo, bout, out);
}

// Round 7
// 194.704 us; speedup vs baseline: 1.1225x; 1.1150x over previous
//
#include <hip/hip_runtime.h>

typedef __bf16 bf16;
typedef __attribute__((ext_vector_type(4))) __bf16 bf16x4;
typedef __attribute__((ext_vector_type(8))) __bf16 bf16x8;
typedef __attribute__((ext_vector_type(4))) float f32x4;

#define MFMA(A,B,C) __builtin_amdgcn_mfma_f32_16x16x32_bf16(A,B,C,0,0,0)

#define SEQ 2048
#define EMB 512
#define HD  64
#define SCALE 22.627416997969522f  // sqrt(512): scores are divided by E^-0.5
// Online-softmax seed: not -inf (fast-math folds inf constants to poison).
#define NEG_SEED -3.0e4f
#define LCAP 24                    // per-query candidate ring capacity

// ---------------------------------------------------------------------------
// One-shot fp32 -> bf16 hi/lo conversion (x, W_qkv) and bf16 (W_out).
// Also zeroes the Vs accumulator (gemm_qkv atomicAdds into it).
// ---------------------------------------------------------------------------
__global__ __launch_bounds__(256)
void convert_kernel(const float* __restrict__ x, const float* __restrict__ Wqkv,
                    const float* __restrict__ Wout,
                    bf16* __restrict__ Xh, bf16* __restrict__ Xl,
                    bf16* __restrict__ Wqh, bf16* __restrict__ Wql,
                    bf16* __restrict__ Wo, float* __restrict__ Vs) {
  if (blockIdx.x < 8) Vs[blockIdx.x * 256 + threadIdx.x] = 0.f;  // 32*64 floats
  const int NX = 8192 * 512 / 4;   // f32x4 chunks
  const int NW = 1536 * 512 / 4;
  const int NO = 512 * 512 / 4;
  const int stride = gridDim.x * 256;
  for (int i = blockIdx.x * 256 + threadIdx.x; i < NX + NW + NO; i += stride) {
    const float* src; bf16 *dh, *dl; int j; bool haslo;
    if (i < NX)           { src = x;    dh = Xh;  dl = Xl;  j = i;           haslo = true; }
    else if (i < NX + NW) { src = Wqkv; dh = Wqh; dl = Wql; j = i - NX;      haslo = true; }
    else                  { src = Wout; dh = Wo;  dl = Wo;  j = i - NX - NW; haslo = false; }
    f32x4 v = *(const f32x4*)&src[(size_t)j * 4];
    bf16x4 h4, l4;
#pragma unroll
    for (int r = 0; r < 4; ++r) {
      bf16 h = (bf16)v[r]; h4[r] = h; l4[r] = (bf16)(v[r] - (float)h);
    }
    *(bf16x4*)&dh[(size_t)j * 4] = h4;
    if (haslo) *(bf16x4*)&dl[(size_t)j * 4] = l4;
  }
}

// ---------------------------------------------------------------------------
// QKV projection: bf16 hi/lo GEMM on pre-converted inputs. XCD-stripe swizzle
// + XOR-chunk LDS. V-tiles (n0%192==128) are hi-only AND fuse the per-head
// V column sums (Vtot) via fp32 atomics.
// ---------------------------------------------------------------------------
__global__ __launch_bounds__(256)
void gemm_qkv(const bf16* __restrict__ Xh, const bf16* __restrict__ Xl,
              const bf16* __restrict__ Wh, const bf16* __restrict__ Wl,
              const float* __restrict__ bias,
              bf16* __restrict__ Qh, bf16* __restrict__ Ql,
              bf16* __restrict__ Kh, bf16* __restrict__ Kl,
              bf16* __restrict__ Vrm, float* __restrict__ Vs) {
  __shared__ __align__(16) bf16 Ah[64][64], Al[64][64];
  __shared__ __align__(16) bf16 Bh[64][64], Bl[64][64];
  const int tid  = threadIdx.x;
  const int lane = tid & 63, wave = tid >> 6;
  const int lin = blockIdx.x + gridDim.x * blockIdx.y;
  const int xcd = lin & 7;
  const int w_  = lin >> 3;                  // 0..383
  const int m0 = ((w_ & 15) + xcd * 16) * 64;
  const int n0 = (w_ >> 4) * 64;
  const bool isV = ((n0 % 192) == 128);      // V third: hi-only suffices
  const int wm = (wave >> 1) * 32, wn = (wave & 1) * 32;
  const int c = lane & 15, quad = lane >> 4;
  const int sr   = tid >> 3;                 // 0..31 staging row
  const int scol = (tid & 7) * 8;
  const int sphy = ((tid & 7) ^ (sr & 7)) * 8;   // (sr+32)&7 == sr&7

  const f32x4 zero = {0.f, 0.f, 0.f, 0.f};
  f32x4 acc[2][2];
  acc[0][0] = zero; acc[0][1] = zero; acc[1][0] = zero; acc[1][1] = zero;

  for (int k0 = 0; k0 < 512; k0 += 64) {
    *(bf16x8*)&Ah[sr][sphy]      = *(const bf16x8*)&Xh[(size_t)(m0 + sr     ) * 512 + k0 + scol];
    *(bf16x8*)&Ah[sr + 32][sphy] = *(const bf16x8*)&Xh[(size_t)(m0 + sr + 32) * 512 + k0 + scol];
    *(bf16x8*)&Bh[sr][sphy]      = *(const bf16x8*)&Wh[(size_t)(n0 + sr     ) * 512 + k0 + scol];
    *(bf16x8*)&Bh[sr + 32][sphy] = *(const bf16x8*)&Wh[(size_t)(n0 + sr + 32) * 512 + k0 + scol];
    if (!isV) {
      *(bf16x8*)&Al[sr][sphy]      = *(const bf16x8*)&Xl[(size_t)(m0 + sr     ) * 512 + k0 + scol];
      *(bf16x8*)&Al[sr + 32][sphy] = *(const bf16x8*)&Xl[(size_t)(m0 + sr + 32) * 512 + k0 + scol];
      *(bf16x8*)&Bl[sr][sphy]      = *(const bf16x8*)&Wl[(size_t)(n0 + sr     ) * 512 + k0 + scol];
      *(bf16x8*)&Bl[sr + 32][sphy] = *(const bf16x8*)&Wl[(size_t)(n0 + sr + 32) * 512 + k0 + scol];
    }
    __syncthreads();
#pragma unroll
    for (int ks = 0; ks < 64; ks += 32) {
      const int px = (((ks >> 3) + quad) ^ (c & 7)) * 8;
      bf16x8 ah0 = *(bf16x8*)&Ah[wm + c     ][px];
      bf16x8 ah1 = *(bf16x8*)&Ah[wm + 16 + c][px];
      bf16x8 bh0 = *(bf16x8*)&Bh[wn + c     ][px];
      bf16x8 bh1 = *(bf16x8*)&Bh[wn + 16 + c][px];
      if (isV) {
        acc[0][0] = MFMA(ah0, bh0, acc[0][0]);
        acc[0][1] = MFMA(ah0, bh1, acc[0][1]);
        acc[1][0] = MFMA(ah1, bh0, acc[1][0]);
        acc[1][1] = MFMA(ah1, bh1, acc[1][1]);
      } else {
        bf16x8 al0 = *(bf16x8*)&Al[wm + c     ][px];
        bf16x8 al1 = *(bf16x8*)&Al[wm + 16 + c][px];
        bf16x8 bl0 = *(bf16x8*)&Bl[wn + c     ][px];
        bf16x8 bl1 = *(bf16x8*)&Bl[wn + 16 + c][px];
        acc[0][0] = MFMA(ah0, bh0, acc[0][0]);
        acc[0][0] = MFMA(al0, bh0, acc[0][0]);
        acc[0][0] = MFMA(ah0, bl0, acc[0][0]);
        acc[0][1] = MFMA(ah0, bh1, acc[0][1]);
        acc[0][1] = MFMA(al0, bh1, acc[0][1]);
        acc[0][1] = MFMA(ah0, bl1, acc[0][1]);
        acc[1][0] = MFMA(ah1, bh0, acc[1][0]);
        acc[1][0] = MFMA(al1, bh0, acc[1][0]);
        acc[1][0] = MFMA(ah1, bl0, acc[1][0]);
        acc[1][1] = MFMA(ah1, bh1, acc[1][1]);
        acc[1][1] = MFMA(al1, bh1, acc[1][1]);
        acc[1][1] = MFMA(ah1, bl1, acc[1][1]);
      }
    }
    __syncthreads();
  }

  if (isV) {
#pragma unroll
    for (int nt = 0; nt < 2; ++nt) {
      const int n = n0 + wn + nt * 16 + c;
      const float bv = bias[n];
      const int h = n / 192, d = n % 192 - 128;
      const size_t bh = (size_t)((m0 >> 11) * 8 + h);
      float csum = 0.f;
#pragma unroll
      for (int mt = 0; mt < 2; ++mt)
#pragma unroll
        for (int r = 0; r < 4; ++r) {
          const int m = m0 + wm + mt * 16 + quad * 4 + r;
          const int s = m & 2047;
          float v = acc[mt][nt][r] + bv;
          Vrm[(bh * SEQ + s) * HD + d] = (bf16)v;
          csum += v;
        }
      csum += __shfl_xor(csum, 16, 64);
      csum += __shfl_xor(csum, 32, 64);
      if (quad == 0) atomicAdd(&Vs[bh * HD + d], csum);
    }
  } else {
#pragma unroll
    for (int mt = 0; mt < 2; ++mt) {
#pragma unroll
      for (int nt = 0; nt < 2; ++nt) {
        const int n = n0 + wn + nt * 16 + c;
        const float bv = bias[n];
#pragma unroll
        for (int r = 0; r < 4; ++r) {
          const int m = m0 + wm + mt * 16 + quad * 4 + r;
          float v = acc[mt][nt][r] + bv;
          const int h = n / 192, t = n % 192;
          const size_t bh = (size_t)((m >> 11) * 8 + h);
          const int s = m & 2047;
          if (t < 64) {
            float q = v * SCALE;
            bf16 hi = (bf16)q;
            float lo = q - (float)hi;
            size_t idx = (bh * SEQ + s) * HD + t;
            Qh[idx] = hi; Ql[idx] = (bf16)lo;
          } else {
            bf16 hi = (bf16)v;
            float lo = v - (float)hi;
            size_t idx = (bh * SEQ + s) * HD + (t - 64);
            Kh[idx] = hi; Kl[idx] = (bf16)lo;
          }
        }
      }
    }
  }
}

// ---------------------------------------------------------------------------
// Output projection: bf16 x bf16 (pre-converted Wo), fp32 out. Same XOR-swz.
// ---------------------------------------------------------------------------
__global__ __launch_bounds__(256)
void gemm_out(const bf16* __restrict__ A, const bf16* __restrict__ Wo,
              const float* __restrict__ bias, float* __restrict__ C) {
  __shared__ __align__(16) bf16 As[64][64];
  __shared__ __align__(16) bf16 Bs[64][64];
  const int tid  = threadIdx.x;
  const int lane = tid & 63, wave = tid >> 6;
  const int lin = blockIdx.x + gridDim.x * blockIdx.y;
  const int xcd = lin & 7;
  const int w_  = lin >> 3;                  // 0..127
  const int m0 = ((w_ & 15) + xcd * 16) * 64;
  const int n0 = (w_ >> 4) * 64;
  const int wm = (wave >> 1) * 32, wn = (wave & 1) * 32;
  const int c = lane & 15, quad = lane >> 4;
  const int sr   = tid >> 3;
  const int scol = (tid & 7) * 8;
  const int sphy = ((tid & 7) ^ (sr & 7)) * 8;

  const f32x4 zero = {0.f, 0.f, 0.f, 0.f};
  f32x4 acc[2][2];
  acc[0][0] = zero; acc[0][1] = zero; acc[1][0] = zero; acc[1][1] = zero;

  for (int k0 = 0; k0 < 512; k0 += 64) {
    *(bf16x8*)&As[sr][sphy]      = *(const bf16x8*)&A [(size_t)(m0 + sr     ) * 512 + k0 + scol];
    *(bf16x8*)&As[sr + 32][sphy] = *(const bf16x8*)&A [(size_t)(m0 + sr + 32) * 512 + k0 + scol];
    *(bf16x8*)&Bs[sr][sphy]      = *(const bf16x8*)&Wo[(size_t)(n0 + sr     ) * 512 + k0 + scol];
    *(bf16x8*)&Bs[sr + 32][sphy] = *(const bf16x8*)&Wo[(size_t)(n0 + sr + 32) * 512 + k0 + scol];
    __syncthreads();
#pragma unroll
    for (int ks = 0; ks < 64; ks += 32) {
      const int px = (((ks >> 3) + quad) ^ (c & 7)) * 8;
      bf16x8 a0 = *(bf16x8*)&As[wm + c     ][px];
      bf16x8 a1 = *(bf16x8*)&As[wm + 16 + c][px];
      bf16x8 b0 = *(bf16x8*)&Bs[wn + c     ][px];
      bf16x8 b1 = *(bf16x8*)&Bs[wn + 16 + c][px];
      acc[0][0] = MFMA(a0, b0, acc[0][0]);
      acc[0][1] = MFMA(a0, b1, acc[0][1]);
      acc[1][0] = MFMA(a1, b0, acc[1][0]);
      acc[1][1] = MFMA(a1, b1, acc[1][1]);
    }
    __syncthreads();
  }

#pragma unroll
  for (int mt = 0; mt < 2; ++mt) {
#pragma unroll
    for (int nt = 0; nt < 2; ++nt) {
      const int n = n0 + wn + nt * 16 + c;
      const float bv = bias[n];
#pragma unroll
      for (int r = 0; r < 4; ++r) {
        const int m = m0 + wm + mt * 16 + quad * 4 + r;
        C[(size_t)m * 512 + n] = acc[mt][nt][r] + bv;
      }
    }
  }
}

// ---------------------------------------------------------------------------
// Attention, double softmax, candidate-index form.
// Math: O = [Vtot + sum_k (t_k-1) V_k]/l2, t = exp(exp(s-m)/l1). Only keys
// within ~3 of the max matter (>1e-4 in O); anything further gives t-1 ~ 0.
// SCAN (dense, staged, branch-light): 2 hi-MFMA/tile, running per-query max
//   (quad-shared every 2 tiles), push key INDEX when sc > mr-12 into a
//   per-query ring list (cap 24, expected ~12). Hi-only err (+-4) + window 12
//   guarantees every key within gap-4 of the exact max is listed. No exp, no
//   l1, no kl, no rescale chain in the loop -> full ILP, like round-4's SCAN.
// FINISH (barrier-free, per-quad): exact fp32 VALU dot for listed keys
//   (lane owns 16 dims; Kh+Kl rows from L2), exact max, l1 = sum exp (exact
//   by shift-invariance), t-1 = exp(p/l1)-1, V-row gather, add Vtot.
// ---------------------------------------------------------------------------
__global__ __launch_bounds__(256, 4)
void attn_kernel(const bf16* __restrict__ Qh, const bf16* __restrict__ Ql,
                 const bf16* __restrict__ Kh, const bf16* __restrict__ Kl,
                 const bf16* __restrict__ Vrm, const float* __restrict__ Vs,
                 bf16* __restrict__ O) {
  __shared__ __align__(16) bf16 SK[2][64][64];        // 16KB Kh stage
  __shared__ float sS[4][16][LCAP];                    // exact-s scratch
  __shared__ unsigned short sI[4][16][LCAP];           // candidate key idx
  __shared__ int pcnt[4][16];

  const int tid  = threadIdx.x;
  const int lane = tid & 63, wave = tid >> 6;
  const int c = lane & 15, quad = lane >> 4;
  const int bh = blockIdx.x;
  const int q0 = blockIdx.y * 64 + wave * 16;
  const size_t hoff = (size_t)bh * SEQ * HD;
  const bf16* qh_p = Qh + hoff;
  const bf16* ql_p = Ql + hoff;
  const bf16* kh_p = Kh + hoff;
  const bf16* kl_p = Kl + hoff;
  const bf16* v_p  = Vrm + hoff;
  const f32x4 zero = {0.f, 0.f, 0.f, 0.f};

  const int sr   = tid >> 3;                          // 0..31 staging row
  const int scol = (tid & 7) * 8;
  const int sphy = ((tid & 7) ^ (sr & 7)) * 8;
  const int pc0  = ((0 + quad) ^ (c & 7)) * 8;
  const int pc1  = ((4 + quad) ^ (c & 7)) * 8;

  bf16x8 qf[2], qlf[2];
#pragma unroll
  for (int t = 0; t < 2; ++t) {
    size_t off = (size_t)(q0 + c) * HD + t * 32 + quad * 8;
    qf[t]  = *(const bf16x8*)&qh_p[off];
    qlf[t] = *(const bf16x8*)&ql_p[off];
  }
  if (lane < 16) pcnt[wave][lane] = 0;   // same-wave use only

  // ================= SCAN: dense hi-only, index collection =================
  bf16x8 pA = *(const bf16x8*)&kh_p[(size_t)(sr     ) * HD + scol];
  bf16x8 pB = *(const bf16x8*)&kh_p[(size_t)(sr + 32) * HD + scol];
  *(bf16x8*)&SK[0][sr     ][sphy] = pA;
  *(bf16x8*)&SK[0][sr + 32][sphy] = pB;
  __syncthreads();

  float mr = NEG_SEED;
  int buf = 0;
  for (int cs = 0; cs < 32; ++cs) {
    if (cs < 31) {
      const size_t k0 = (size_t)(cs + 1) * 64;
      pA = *(const bf16x8*)&kh_p[(k0 + sr     ) * HD + scol];
      pB = *(const bf16x8*)&kh_p[(k0 + sr + 32) * HD + scol];
    }
#pragma unroll
    for (int t = 0; t < 4; ++t) {
      const int g = cs * 4 + t;
      bf16x8 kh0 = *(bf16x8*)&SK[buf][t * 16 + c][pc0];
      bf16x8 kh1 = *(bf16x8*)&SK[buf][t * 16 + c][pc1];
      f32x4 sc = MFMA(kh0, qf[0], zero);
      sc = MFMA(kh1, qf[1], sc);
      const float tm = fmaxf(fmaxf(sc[0], sc[1]), fmaxf(sc[2], sc[3]));
      mr = fmaxf(mr, tm);
      if (t & 1) {   // quad-share the running max every 2 tiles
        mr = fmaxf(mr, __shfl_xor(mr, 16, 64));
        mr = fmaxf(mr, __shfl_xor(mr, 32, 64));
      }
      if (tm > mr - 12.f) {
#pragma unroll
        for (int r = 0; r < 4; ++r) {
          if (sc[r] > mr - 12.f) {
            const int slot = atomicAdd(&pcnt[wave][c], 1) % LCAP;  // ring
            sI[wave][c][slot] = (unsigned short)(g * 16 + quad * 4 + r);
          }
        }
      }
    }
    if (cs < 31) {
      const int nb = buf ^ 1;
      *(bf16x8*)&SK[nb][sr     ][sphy] = pA;
      *(bf16x8*)&SK[nb][sr + 32][sphy] = pB;
      __syncthreads();
      buf = nb;
    }
  }

  // ================= FINISH: exact, per-quad, barrier-free =================
  // lane's fp32 slice of its query (16 dims: quad*8..+8 and 32+quad*8..+8)
  float qv[16];
#pragma unroll
  for (int j = 0; j < 8; ++j) {
    qv[j]     = (float)qf[0][j] + (float)qlf[0][j];
    qv[8 + j] = (float)qf[1][j] + (float)qlf[1][j];
  }
  const int n = min(pcnt[wave][c], LCAP);
  float mqC = NEG_SEED;
  for (int j = 0; j < n; ++j) {
    const int idx = sI[wave][c][j];
    const size_t kr = (size_t)idx * HD + quad * 8;
    bf16x8 kh0 = *(const bf16x8*)&kh_p[kr];
    bf16x8 kh1 = *(const bf16x8*)&kh_p[kr + 32];
    bf16x8 kl0 = *(const bf16x8*)&kl_p[kr];
    bf16x8 kl1 = *(const bf16x8*)&kl_p[kr + 32];
    float s = 0.f;
#pragma unroll
    for (int jj = 0; jj < 8; ++jj) {
      s = fmaf(qv[jj],     (float)kh0[jj] + (float)kl0[jj], s);
      s = fmaf(qv[8 + jj], (float)kh1[jj] + (float)kl1[jj], s);
    }
    s += __shfl_xor(s, 16, 64);
    s += __shfl_xor(s, 32, 64);
    if (quad == 0) sS[wave][c][j] = s;
    mqC = fmaxf(mqC, s);
  }
  float l1 = 0.f;
  for (int j = 0; j < n; ++j) l1 += __expf(sS[wave][c][j] - mqC);
  const float inv1 = 1.f / l1;

  float oc[16];
#pragma unroll
  for (int i = 0; i < 16; ++i) oc[i] = 0.f;
  float l2 = 0.f;
  for (int j = 0; j < n; ++j) {
    const float a1 = __expf(sS[wave][c][j] - mqC) * inv1;  // attn1 in [0,1]
    const float t1 = __expf(a1) - 1.0f;                    // t-1
    l2 += t1;
    const int idx = sI[wave][c][j];
    bf16x8 v0 = *(const bf16x8*)&v_p[(size_t)idx * HD + quad * 8];
    bf16x8 v1 = *(const bf16x8*)&v_p[(size_t)idx * HD + 32 + quad * 8];
#pragma unroll
    for (int jj = 0; jj < 8; ++jj) {
      oc[jj]     += t1 * (float)v0[jj];
      oc[8 + jj] += t1 * (float)v1[jj];
    }
  }

  const int b = bh >> 3, h = bh & 7;
  const float rcp = 1.f / (2048.f + l2);
  const float* vsp = Vs + bh * HD;
  bf16* orow = &O[((size_t)b * SEQ + q0 + c) * EMB + h * HD];
  bf16x8 o0, o1;
#pragma unroll
  for (int jj = 0; jj < 8; ++jj) {
    o0[jj] = (bf16)((oc[jj]     + vsp[quad * 8 + jj])      * rcp);
    o1[jj] = (bf16)((oc[8 + jj] + vsp[32 + quad * 8 + jj]) * rcp);
  }
  *(bf16x8*)&orow[quad * 8]      = o0;
  *(bf16x8*)&orow[32 + quad * 8] = o1;
}

// ---------------------------------------------------------------------------
extern "C" void kernel_launch(void* const* d_in, const int* in_sizes, int n_in,
                              void* d_out, int out_size, void* d_ws, size_t ws_size,
                              hipStream_t stream) {
  const float* x    = (const float*)d_in[0];
  const float* Wqkv = (const float*)d_in[1];
  const float* bqkv = (const float*)d_in[2];
  const float* Wout = (const float*)d_in[3];
  const float* bout = (const float*)d_in[4];
  float* out = (float*)d_out;

  char* ws = (char*)d_ws;
  const size_t SZ = (size_t)32 * SEQ * HD * 2;  // 8 MiB per array
  bf16* Qh  = (bf16*)(ws + 0 * SZ);
  bf16* Ql  = (bf16*)(ws + 1 * SZ);
  bf16* Kh  = (bf16*)(ws + 2 * SZ);
  bf16* Kl  = (bf16*)(ws + 3 * SZ);
  bf16* Vrm = (bf16*)(ws + 4 * SZ);
  bf16* XhO = (bf16*)(ws + 5 * SZ);  // Xh during proj; overwritten by O in attn
  bf16* Xl  = (bf16*)(ws + 6 * SZ);
  bf16* Wqh = (bf16*)(ws + 7 * SZ);
  bf16* Wql = (bf16*)(ws + 7 * SZ + 0x180000);
  bf16* Wo  = (bf16*)(ws + 7 * SZ + 0x300000);
  float* Vs = (float*)(ws + 7 * SZ + 0x380000);  // 32x64 f32 Vtot (atomics)

  convert_kernel<<<dim3(2048), 256, 0, stream>>>(x, Wqkv, Wout, XhO, Xl, Wqh, Wql, Wo, Vs);
  gemm_qkv<<<dim3(128, 24), 256, 0, stream>>>(XhO, Xl, Wqh, Wql, bqkv, Qh, Ql, Kh, Kl, Vrm, Vs);
  attn_kernel<<<dim3(32, 32), 256, 0, stream>>>(Qh, Ql, Kh, Kl, Vrm, Vs, XhO);
  gemm_out<<<dim3(128, 8), 256, 0, stream>>>(XhO, Wo, bout, out);
}